// Round 1
// baseline (41.135 us; speedup 1.0000x reference)
//
#include <hip/hip_runtime.h>
#include <math.h>

// Problem constants (fixed by setup_inputs)
#define B_   8
#define S_   512
#define MV_  8        // M_VALID
#define D_   512
#define R_   16
#define MOUT (R_ + 1) // 17 output slots per (b,s)

// ---------------------------------------------------------------------------
// Kernel 1: materialize sinusoidal PE table, pe[S][D] (1 MB) into workspace.
// pe[s][2j]   = sin(s * exp(-2j*ln(10000)/D))
// pe[s][2j+1] = cos(s * exp(-2j*ln(10000)/D))
// 131072 pairs -> 512 blocks x 256 threads. Accurate sincosf (cost negligible).
// ---------------------------------------------------------------------------
__global__ __launch_bounds__(256) void pe_table_kernel(float* __restrict__ pe) {
    int idx = blockIdx.x * 256 + threadIdx.x;   // 0 .. S*D/2-1
    int s = idx >> 8;                           // / (D/2)
    int j = idx & 255;                          // pair index
    const float kNegLn10kOverD = -9.210340371976184f / (float)D_;
    float freq  = expf((float)(2 * j) * kNegLn10kOverD);
    float angle = (float)s * freq;
    float sn, cs;
    sincosf(angle, &sn, &cs);
    pe[s * D_ + 2 * j]     = sn;
    pe[s * D_ + 2 * j + 1] = cs;
}

// ---------------------------------------------------------------------------
// Kernel 2: main fused gather + add.
// One block per output row (b,s,m); 128 threads x float4 = 512 floats.
// Branches (m==0, idx<MV) are block-uniform -> no lane divergence.
// ---------------------------------------------------------------------------
template <bool INLINE_PE>
__global__ __launch_bounds__(128) void block_revert_kernel(
    const float* __restrict__ temporal,   // [B][S][MV+1][D]
    const float* __restrict__ mask_token, // [D]
    const float* __restrict__ mod_emb,    // [R+1][D]
    const int*   __restrict__ revert_idx, // [B][S][R]
    const float* __restrict__ pe,         // [S][D] (may be null if INLINE_PE)
    float*       __restrict__ out)        // [B][S][MOUT][D]
{
    int row = blockIdx.x;                 // 0 .. B*S*MOUT-1
    int m   = row % MOUT;
    int bs  = row / MOUT;                 // b*S + s
    int s   = bs & (S_ - 1);

    // Resolve gather source (wave-uniform)
    const float* src;
    if (m == 0) {
        src = temporal + (size_t)bs * (MV_ + 1) * D_;             // global slot
    } else {
        int idx = revert_idx[bs * R_ + (m - 1)];
        if (idx < MV_)
            src = temporal + ((size_t)bs * (MV_ + 1) + 1 + idx) * D_;
        else
            src = mask_token;                                      // mask fill
    }

    int d = threadIdx.x * 4;

    float4 v  = *reinterpret_cast<const float4*>(src + d);
    float4 me = *reinterpret_cast<const float4*>(mod_emb + m * D_ + d);

    float4 p;
    if (INLINE_PE) {
        // pairs j0 = d/2, j1 = d/2+1
        const float kNegLn10kOverD = -9.210340371976184f / (float)D_;
        float f0 = __expf((float)(2 * (d >> 1))     * kNegLn10kOverD);
        float f1 = __expf((float)(2 * ((d >> 1)+1)) * kNegLn10kOverD);
        float a0 = (float)s * f0, a1 = (float)s * f1;
        __sincosf(a0, &p.x, &p.y);
        __sincosf(a1, &p.z, &p.w);
    } else {
        p = *reinterpret_cast<const float4*>(pe + s * D_ + d);
    }

    float4 o;
    o.x = v.x + p.x + me.x;
    o.y = v.y + p.y + me.y;
    o.z = v.z + p.z + me.z;
    o.w = v.w + p.w + me.w;

    *reinterpret_cast<float4*>(out + (size_t)row * D_ + d) = o;
}

extern "C" void kernel_launch(void* const* d_in, const int* in_sizes, int n_in,
                              void* d_out, int out_size, void* d_ws, size_t ws_size,
                              hipStream_t stream) {
    const float* temporal   = (const float*)d_in[0];
    const float* mask_token = (const float*)d_in[1];
    const float* mod_emb    = (const float*)d_in[2];
    const int*   revert_idx = (const int*)d_in[3];
    float*       out        = (float*)d_out;

    const int n_rows = B_ * S_ * MOUT;           // 69632
    const size_t pe_bytes = (size_t)S_ * D_ * sizeof(float); // 1 MB

    if (ws_size >= pe_bytes) {
        float* pe = (float*)d_ws;
        pe_table_kernel<<<(S_ * D_ / 2) / 256, 256, 0, stream>>>(pe);
        block_revert_kernel<false><<<n_rows, 128, 0, stream>>>(
            temporal, mask_token, mod_emb, revert_idx, pe, out);
    } else {
        block_revert_kernel<true><<<n_rows, 128, 0, stream>>>(
            temporal, mask_token, mod_emb, revert_idx, nullptr, out);
    }
}

// Round 3
// 32.710 us; speedup vs baseline: 1.2576x; 1.2576x over previous
//
#include <hip/hip_runtime.h>
#include <math.h>

// Problem constants (fixed by setup_inputs)
#define B_   8
#define S_   512
#define MV_  8        // M_VALID
#define D_   512
#define R_   16
#define MOUT (R_ + 1)            // 17 output slots per (b,s)
#define F4_PER_ROW (D_ / 4)      // 128
#define F4_PER_BS  (MOUT * F4_PER_ROW) // 2176

typedef float f32x4 __attribute__((ext_vector_type(4)));  // native vec for nontemporal builtins

// One block per (b,s): compute PE row once into LDS, preload 16 gather
// indices, then stream 17 rows of gather+add with float4 / nontemporal
// stores. All gather branches are wave-uniform (64 consecutive float4s
// per wave stay within one output row half).
__global__ __launch_bounds__(256) void block_revert_fused(
    const float* __restrict__ temporal,   // [B][S][MV+1][D]
    const float* __restrict__ mask_token, // [D]
    const float* __restrict__ mod_emb,    // [R+1][D]
    const int*   __restrict__ revert_idx, // [B][S][R]
    float*       __restrict__ out)        // [B][S][MOUT][D]
{
    __shared__ float s_pe[D_];
    __shared__ int   s_idx[R_];

    const int bs = blockIdx.x;            // b*S + s
    const int s  = bs & (S_ - 1);
    const int t  = threadIdx.x;

    // PE row for this s: thread t computes pair j = t (D/2 = 256 pairs).
    // Accurate expf/sincosf: 1 each per thread per block, amortized 17x.
    {
        const float kNegLn10kOverD = -9.210340371976184f / (float)D_;
        float freq = expf((float)(2 * t) * kNegLn10kOverD);
        float sn, cs;
        sincosf((float)s * freq, &sn, &cs);
        s_pe[2 * t]     = sn;
        s_pe[2 * t + 1] = cs;
    }
    if (t < R_) s_idx[t] = revert_idx[bs * R_ + t];
    __syncthreads();

    const float* base = temporal + (size_t)bs * (MV_ + 1) * D_;
    float*       outb = out + (size_t)bs * MOUT * D_;

    for (int f4 = t; f4 < F4_PER_BS; f4 += 256) {
        int m  = f4 >> 7;          // output row 0..16 (wave-uniform)
        int d4 = (f4 & 127) * 4;   // float offset within row

        const float* src;
        if (m == 0) {
            src = base;                                   // global slot
        } else {
            int idx = s_idx[m - 1];
            src = (idx < MV_) ? (base + (size_t)(1 + idx) * D_)
                              : mask_token;               // mask fill
        }

        f32x4 v  = *reinterpret_cast<const f32x4*>(src + d4);
        f32x4 p  = *reinterpret_cast<const f32x4*>(s_pe + d4);
        f32x4 me = *reinterpret_cast<const f32x4*>(mod_emb + m * D_ + d4);

        f32x4 o = v + p + me;

        __builtin_nontemporal_store(o,
            reinterpret_cast<f32x4*>(outb + (size_t)m * D_ + d4));
    }
}

extern "C" void kernel_launch(void* const* d_in, const int* in_sizes, int n_in,
                              void* d_out, int out_size, void* d_ws, size_t ws_size,
                              hipStream_t stream) {
    const float* temporal   = (const float*)d_in[0];
    const float* mask_token = (const float*)d_in[1];
    const float* mod_emb    = (const float*)d_in[2];
    const int*   revert_idx = (const int*)d_in[3];
    float*       out        = (float*)d_out;

    block_revert_fused<<<B_ * S_, 256, 0, stream>>>(
        temporal, mask_token, mod_emb, revert_idx, out);
}